// Round 1
// baseline (105.750 us; speedup 1.0000x reference)
//
#include <hip/hip_runtime.h>

#define G 64
#define BLOCK 256
#define NBLOCKS 1280   // 5 blocks/CU * 256 CUs: all resident (32KB LDS -> 5/CU cap), table staged once per block

__global__ __launch_bounds__(BLOCK) void crs_kernel(
    const float2* __restrict__ ch1,
    const float2* __restrict__ ch2,
    const float4* __restrict__ cp,    // CP_locs viewed as float4 (G*G/2 of them)
    const int2*  __restrict__ idx,
    float* __restrict__ out, int n)
{
    __shared__ float2 lds_cp[G * G];     // 32 KB
    __shared__ float  wave_sums[BLOCK / 64];

    // Stage CP_locs -> LDS, vectorized 16B: 2048 float4s, 8 per thread.
    {
        float4* lds4 = (float4*)lds_cp;
        #pragma unroll
        for (int i = threadIdx.x; i < (G * G) / 2; i += BLOCK)
            lds4[i] = cp[i];
    }
    __syncthreads();

    float acc = 0.0f;
    const int stride = NBLOCKS * BLOCK;
    for (int t = blockIdx.x * BLOCK + threadIdx.x; t < n; t += stride) {
        const float2 c2 = ch2[t];
        const int2   ij = idx[t];
        const float2 c1 = ch1[t];

        const float x = c2.x - floorf(c2.x);
        const float y = c2.y - floorf(c2.y);

        // Catmull-Rom weights: w = [x^3, x^2, x, 1] @ A
        float wxv[4], wyv[4];
        wxv[0] = ((-0.5f * x + 1.0f) * x - 0.5f) * x;
        wxv[1] = (1.5f * x - 2.5f) * x * x + 1.0f;
        wxv[2] = ((-1.5f * x + 2.0f) * x + 0.5f) * x;
        wxv[3] = (0.5f * x - 0.5f) * x * x;
        wyv[0] = ((-0.5f * y + 1.0f) * y - 0.5f) * y;
        wyv[1] = (1.5f * y - 2.5f) * y * y + 1.0f;
        wyv[2] = ((-1.5f * y + 2.0f) * y + 0.5f) * y;
        wyv[3] = (0.5f * y - 0.5f) * y * y;

        // Q[i][j] = CP_locs[ij.x-1+i][ij.y-1+j]; out_c = sum_ij wx[i]*wy[j]*Q[i][j][c]
        const int base = (ij.x - 1) * G + (ij.y - 1);
        float s0 = 0.0f, s1 = 0.0f;
        #pragma unroll
        for (int i = 0; i < 4; ++i) {
            float r0 = 0.0f, r1 = 0.0f;
            #pragma unroll
            for (int j = 0; j < 4; ++j) {
                const float2 q = lds_cp[base + i * G + j];
                r0 = fmaf(wyv[j], q.x, r0);
                r1 = fmaf(wyv[j], q.y, r1);
            }
            s0 = fmaf(wxv[i], r0, s0);
            s1 = fmaf(wxv[i], r1, s1);
        }

        const float d0 = c1.x - s0;
        const float d1 = c1.y - s1;
        acc = fmaf(d0, d0, acc);
        acc = fmaf(d1, d1, acc);
    }

    // Wave-64 butterfly reduce, then cross-wave via LDS, one atomic per block.
    #pragma unroll
    for (int off = 32; off > 0; off >>= 1)
        acc += __shfl_down(acc, off, 64);

    const int lane = threadIdx.x & 63;
    const int wave = threadIdx.x >> 6;
    if (lane == 0) wave_sums[wave] = acc;
    __syncthreads();
    if (threadIdx.x == 0) {
        float s = 0.0f;
        #pragma unroll
        for (int w = 0; w < BLOCK / 64; ++w) s += wave_sums[w];
        atomicAdd(out, s);
    }
}

extern "C" void kernel_launch(void* const* d_in, const int* in_sizes, int n_in,
                              void* d_out, int out_size, void* d_ws, size_t ws_size,
                              hipStream_t stream) {
    const float2* ch1 = (const float2*)d_in[0];
    const float2* ch2 = (const float2*)d_in[1];
    const float4* cp  = (const float4*)d_in[2];   // CP_locs (G,G,2) f32
    const int2*   idx = (const int2*)d_in[3];
    float* out = (float*)d_out;
    const int n = in_sizes[0] / 2;   // N points

    // d_out is poisoned to 0xAA before every timed launch; zero it on-stream.
    hipMemsetAsync(out, 0, sizeof(float), stream);
    crs_kernel<<<NBLOCKS, BLOCK, 0, stream>>>(ch1, ch2, cp, idx, out, n);
}